// Round 1
// baseline (637.799 us; speedup 1.0000x reference)
//
#include <hip/hip_runtime.h>

#define DEVI __device__ __forceinline__

typedef float f32x4 __attribute__((ext_vector_type(4)));
typedef __bf16 bf16x8 __attribute__((ext_vector_type(8)));

constexpr int S   = 2048;
constexpr int HID = 1024;
constexpr int NH  = 16;
constexpr int HD  = 64;
constexpr int O3  = 3072;
constexpr int KF  = 9216;   // 1024 silu + 1024*8 spline

DEVI unsigned short f2bf(float f) {
  unsigned int u = __float_as_uint(f);
  u = (u + 0x7FFFu + ((u >> 16) & 1u)) >> 16;
  return (unsigned short)u;
}

DEVI void gload16(const void* g, void* l) {
  __builtin_amdgcn_global_load_lds((const __attribute__((address_space(1))) void*)g,
                                   (__attribute__((address_space(3))) void*)l, 16, 0, 0);
}

// ---- build bf16 combined weight Wc[3072][9216] = [base | spline*scaler] ----
__global__ __launch_bounds__(256) void kconv_w(const float* __restrict__ bw,
    const float* __restrict__ sw, const float* __restrict__ sc,
    unsigned short* __restrict__ Wc) {
  unsigned int t = blockIdx.x * 256 + threadIdx.x;    // < 3072*1152
  unsigned int o = t / 1152, jc = t % 1152;
  unsigned int j = jc * 8;
  float v[8];
  if (j < 1024) {
    const float4* p = (const float4*)(bw + (size_t)o * 1024 + j);
    float4 a = p[0], b = p[1];
    v[0]=a.x; v[1]=a.y; v[2]=a.z; v[3]=a.w; v[4]=b.x; v[5]=b.y; v[6]=b.z; v[7]=b.w;
  } else {
    unsigned int i = (j - 1024) >> 3;
    float s = sc[(size_t)o * 1024 + i];
    const float4* p = (const float4*)(sw + ((size_t)o * 1024 + i) * 8);
    float4 a = p[0], b = p[1];
    v[0]=a.x*s; v[1]=a.y*s; v[2]=a.z*s; v[3]=a.w*s; v[4]=b.x*s; v[5]=b.y*s; v[6]=b.z*s; v[7]=b.w*s;
  }
  union { unsigned short u[8]; uint4 q; } pk;
  #pragma unroll
  for (int c = 0; c < 8; ++c) pk.u[c] = f2bf(v[c]);
  *(uint4*)(Wc + (size_t)o * KF + j) = pk.q;
}

__global__ __launch_bounds__(256) void kconv_outw(const float* __restrict__ ow,
    unsigned short* __restrict__ Wo) {
  unsigned int t = blockIdx.x * 256 + threadIdx.x;    // < 131072
  unsigned int o = t >> 7, j = (t & 127) * 8;
  const float4* p = (const float4*)(ow + (size_t)o * 1024 + j);
  float4 a = p[0], b = p[1];
  float v[8] = {a.x, a.y, a.z, a.w, b.x, b.y, b.z, b.w};
  union { unsigned short u[8]; uint4 q; } pk;
  #pragma unroll
  for (int c = 0; c < 8; ++c) pk.u[c] = f2bf(v[c]);
  *(uint4*)(Wo + (size_t)o * 1024 + j) = pk.q;
}

// ---- features F[2048][9216] bf16 : [silu(x) | b_splines(x)] ----
__global__ __launch_bounds__(256) void kfeatures(const float* __restrict__ x,
    const float* __restrict__ grid, unsigned short* __restrict__ F) {
  unsigned int t = blockIdx.x * 256 + threadIdx.x;    // < 2048*1024
  unsigned int n = t >> 10, i = t & 1023;
  float xv = x[t];
  float sil = xv / (1.f + expf(-xv));
  F[(size_t)n * KF + i] = f2bf(sil);
  float g[12];
  #pragma unroll
  for (int j = 0; j < 12; ++j) g[j] = grid[i * 12 + j];
  float b[11];
  #pragma unroll
  for (int j = 0; j < 11; ++j) b[j] = (xv >= g[j] && xv < g[j + 1]) ? 1.f : 0.f;
  #pragma unroll
  for (int ord = 1; ord <= 3; ++ord)
    #pragma unroll
    for (int j = 0; j + ord < 11; ++j)
      b[j] = (xv - g[j]) / (g[j + ord] - g[j]) * b[j]
           + (g[j + ord + 1] - xv) / (g[j + ord + 1] - g[j + 1]) * b[j + 1];
  union { unsigned short u[8]; uint4 q; } pk;
  #pragma unroll
  for (int c = 0; c < 8; ++c) pk.u[c] = f2bf(b[c]);
  *(uint4*)(F + (size_t)n * KF + 1024 + i * 8) = pk.q;
}

// ---- m97-style 128x128 bf16 GEMM: C[M][N] = A[M][K] @ W[N][K]^T (+bias) ----
__global__ __launch_bounds__(256) void kgemm_bt(const unsigned short* __restrict__ A,
    const unsigned short* __restrict__ W, float* __restrict__ C,
    const float* __restrict__ bias, int N, int K, int addBias) {
  const int bm = blockIdx.x, bn = blockIdx.y;
  const int tid = threadIdx.x;
  const int w = tid >> 6, lane = tid & 63;
  const int l16 = lane & 15, g4 = lane >> 4;
  const int wr = w >> 1, wc = w & 1;
  __shared__ __align__(16) unsigned short As[128 * 32];
  __shared__ __align__(16) unsigned short Bs[128 * 32];
  f32x4 acc[4][4] = {};
  const int nk = K >> 5;
  for (int kt = 0; kt < nk; ++kt) {
    #pragma unroll
    for (int r = 0; r < 2; ++r) {
      int chunk = r * 256 + w * 64 + lane;
      int row = chunk >> 2, col = (chunk & 3) * 8;
      int ldsoff = (r * 256 + w * 64) * 16;
      gload16(A + (size_t)(bm * 128 + row) * K + kt * 32 + col, (char*)As + ldsoff);
      gload16(W + (size_t)(bn * 128 + row) * K + kt * 32 + col, (char*)Bs + ldsoff);
    }
    asm volatile("s_waitcnt vmcnt(0)" ::: "memory");
    __syncthreads();
    bf16x8 af[4], bf[4];
    #pragma unroll
    for (int f = 0; f < 4; ++f)
      af[f] = *(const bf16x8*)(As + (wr * 64 + f * 16 + l16) * 32 + g4 * 8);
    #pragma unroll
    for (int f = 0; f < 4; ++f)
      bf[f] = *(const bf16x8*)(Bs + (wc * 64 + f * 16 + l16) * 32 + g4 * 8);
    #pragma unroll
    for (int fr = 0; fr < 4; ++fr)
      #pragma unroll
      for (int fc = 0; fc < 4; ++fc)
        acc[fr][fc] = __builtin_amdgcn_mfma_f32_16x16x32_bf16(af[fr], bf[fc], acc[fr][fc], 0, 0, 0);
    __syncthreads();
  }
  #pragma unroll
  for (int fr = 0; fr < 4; ++fr) {
    int rowb = bm * 128 + wr * 64 + fr * 16 + g4 * 4;
    #pragma unroll
    for (int fc = 0; fc < 4; ++fc) {
      int col = bn * 128 + wc * 64 + fc * 16 + l16;
      float bv = addBias ? bias[col] : 0.f;
      #pragma unroll
      for (int rg = 0; rg < 4; ++rg)
        C[(size_t)(rowb + rg) * N + col] = acc[fr][fc][rg] + bv;
    }
  }
}

// ---- RoPE on q,k -> per-head bf16 Qb/Kb [h][n][d] ----
__global__ __launch_bounds__(256) void krope_qk(const float* __restrict__ qkv,
    const float* __restrict__ rc, const float* __restrict__ rs,
    unsigned short* __restrict__ Qb, unsigned short* __restrict__ Kb) {
  unsigned int t = blockIdx.x * 256 + threadIdx.x;    // < 2048*16*32
  int d = t & 31;
  int h = (t >> 5) & 15;
  int n = t >> 9;
  const float* row = qkv + (size_t)n * O3 + h * 192;
  float c = rc[n * 32 + d], s = rs[n * 32 + d];
  float qr = row[2 * d], qi = row[2 * d + 1];
  float kr = row[64 + 2 * d], ki = row[64 + 2 * d + 1];
  unsigned int qp = (unsigned int)f2bf(qr * c - qi * s) | ((unsigned int)f2bf(qr * s + qi * c) << 16);
  unsigned int kp = (unsigned int)f2bf(kr * c - ki * s) | ((unsigned int)f2bf(kr * s + ki * c) << 16);
  *(unsigned int*)(Qb + (size_t)h * S * HD + (size_t)n * HD + 2 * d) = qp;
  *(unsigned int*)(Kb + (size_t)h * S * HD + (size_t)n * HD + 2 * d) = kp;
}

// ---- pack V transposed: Vt[h][d][n] bf16 (LDS transpose per 64x64 tile) ----
__global__ __launch_bounds__(256) void kpack_vt(const float* __restrict__ qkv,
    unsigned short* __restrict__ Vt) {
  const int nt = blockIdx.x;   // 0..31
  const int h  = blockIdx.y;   // 0..15
  const int tid = threadIdx.x;
  __shared__ __align__(16) unsigned short T[64][72];
  const int n0 = nt * 64;
  #pragma unroll
  for (int it = 0; it < 4; ++it) {
    int idx = it * 256 + tid;          // 0..1023
    int r = idx >> 4;                  // n offset
    int c4 = (idx & 15) * 4;           // d offset
    float4 v = *(const float4*)(qkv + (size_t)(n0 + r) * O3 + h * 192 + 128 + c4);
    T[c4 + 0][r] = f2bf(v.x);
    T[c4 + 1][r] = f2bf(v.y);
    T[c4 + 2][r] = f2bf(v.z);
    T[c4 + 3][r] = f2bf(v.w);
  }
  __syncthreads();
  #pragma unroll
  for (int it = 0; it < 2; ++it) {
    int idx = it * 256 + tid;          // 0..511
    int d = idx >> 3;
    int c8 = (idx & 7) * 8;
    *(uint4*)(Vt + (size_t)h * HD * S + (size_t)d * S + n0 + c8) = *(const uint4*)&T[d][c8];
  }
}

// ---- flash attention: 4 waves x 32 q-rows, KV tiles of 64 ----
__global__ __launch_bounds__(256) void kattn(const unsigned short* __restrict__ Qb,
    const unsigned short* __restrict__ Kb, const unsigned short* __restrict__ Vt,
    unsigned short* __restrict__ ctx) {
  const int qb = blockIdx.x, h = blockIdx.y;
  const int tid = threadIdx.x, w = tid >> 6, lane = tid & 63;
  const int l16 = lane & 15, g4 = lane >> 4;
  __shared__ __align__(16) unsigned short Ks[64 * 64];
  __shared__ __align__(16) unsigned short Vs[64 * 64];
  __shared__ __align__(16) unsigned short Ps[4][32 * 64];
  const unsigned short* Qh = Qb + (size_t)h * S * HD;
  const unsigned short* Kh = Kb + (size_t)h * S * HD;
  const unsigned short* Vh = Vt + (size_t)h * HD * S;
  bf16x8 qf[2][2];
  #pragma unroll
  for (int fr = 0; fr < 2; ++fr)
    #pragma unroll
    for (int ks = 0; ks < 2; ++ks)
      qf[fr][ks] = *(const bf16x8*)(Qh + (size_t)(qb * 128 + w * 32 + fr * 16 + l16) * HD + ks * 32 + g4 * 8);
  f32x4 o[2][4] = {};
  float mrun[2][4], lrun[2][4];
  #pragma unroll
  for (int fr = 0; fr < 2; ++fr)
    #pragma unroll
    for (int rg = 0; rg < 4; ++rg) { mrun[fr][rg] = -1e30f; lrun[fr][rg] = 0.f; }

  for (int t = 0; t < S / 64; ++t) {
    int kv0 = t * 64;
    #pragma unroll
    for (int r = 0; r < 2; ++r) {
      int chunk = r * 256 + w * 64 + lane;
      int row = chunk >> 3, c8 = (chunk & 7) * 8;
      int ldsoff = (r * 256 + w * 64) * 16;
      gload16(Kh + (size_t)(kv0 + row) * HD + c8, (char*)Ks + ldsoff);
      gload16(Vh + (size_t)row * S + kv0 + c8, (char*)Vs + ldsoff);
    }
    asm volatile("s_waitcnt vmcnt(0)" ::: "memory");
    __syncthreads();
    f32x4 s[2][4] = {};
    #pragma unroll
    for (int fc = 0; fc < 4; ++fc)
      #pragma unroll
      for (int ks = 0; ks < 2; ++ks) {
        bf16x8 bk = *(const bf16x8*)(Ks + (fc * 16 + l16) * 64 + ks * 32 + g4 * 8);
        s[0][fc] = __builtin_amdgcn_mfma_f32_16x16x32_bf16(qf[0][ks], bk, s[0][fc], 0, 0, 0);
        s[1][fc] = __builtin_amdgcn_mfma_f32_16x16x32_bf16(qf[1][ks], bk, s[1][fc], 0, 0, 0);
      }
    #pragma unroll
    for (int fr = 0; fr < 2; ++fr)
      #pragma unroll
      for (int fc = 0; fc < 4; ++fc)
        s[fr][fc] *= 0.125f;
    #pragma unroll
    for (int fr = 0; fr < 2; ++fr) {
      #pragma unroll
      for (int rg = 0; rg < 4; ++rg) {
        float mt = fmaxf(fmaxf(s[fr][0][rg], s[fr][1][rg]), fmaxf(s[fr][2][rg], s[fr][3][rg]));
        mt = fmaxf(mt, __shfl_xor(mt, 1, 64));
        mt = fmaxf(mt, __shfl_xor(mt, 2, 64));
        mt = fmaxf(mt, __shfl_xor(mt, 4, 64));
        mt = fmaxf(mt, __shfl_xor(mt, 8, 64));
        float mn = fmaxf(mrun[fr][rg], mt);
        float al = expf(mrun[fr][rg] - mn);
        float rsum = 0.f;
        #pragma unroll
        for (int fc = 0; fc < 4; ++fc) {
          float p = expf(s[fr][fc][rg] - mn);
          s[fr][fc][rg] = p;
          rsum += p;
        }
        rsum += __shfl_xor(rsum, 1, 64);
        rsum += __shfl_xor(rsum, 2, 64);
        rsum += __shfl_xor(rsum, 4, 64);
        rsum += __shfl_xor(rsum, 8, 64);
        lrun[fr][rg] = lrun[fr][rg] * al + rsum;
        mrun[fr][rg] = mn;
        #pragma unroll
        for (int fc = 0; fc < 4; ++fc)
          o[fr][fc][rg] *= al;
      }
    }
    #pragma unroll
    for (int fr = 0; fr < 2; ++fr)
      #pragma unroll
      for (int fc = 0; fc < 4; ++fc)
        #pragma unroll
        for (int rg = 0; rg < 4; ++rg)
          Ps[w][(fr * 16 + g4 * 4 + rg) * 64 + fc * 16 + l16] = f2bf(s[fr][fc][rg]);
    __syncthreads();
    #pragma unroll
    for (int ks = 0; ks < 2; ++ks) {
      bf16x8 ap0 = *(const bf16x8*)(Ps[w] + (l16) * 64 + ks * 32 + g4 * 8);
      bf16x8 ap1 = *(const bf16x8*)(Ps[w] + (16 + l16) * 64 + ks * 32 + g4 * 8);
      #pragma unroll
      for (int fc = 0; fc < 4; ++fc) {
        bf16x8 bv = *(const bf16x8*)(Vs + (fc * 16 + l16) * 64 + ks * 32 + g4 * 8);
        o[0][fc] = __builtin_amdgcn_mfma_f32_16x16x32_bf16(ap0, bv, o[0][fc], 0, 0, 0);
        o[1][fc] = __builtin_amdgcn_mfma_f32_16x16x32_bf16(ap1, bv, o[1][fc], 0, 0, 0);
      }
    }
    __syncthreads();
  }
  #pragma unroll
  for (int fr = 0; fr < 2; ++fr)
    #pragma unroll
    for (int rg = 0; rg < 4; ++rg) {
      float inv = 1.f / lrun[fr][rg];
      int row = qb * 128 + w * 32 + fr * 16 + g4 * 4 + rg;
      #pragma unroll
      for (int fc = 0; fc < 4; ++fc)
        ctx[(size_t)row * HID + h * HD + fc * 16 + l16] = f2bf(o[fr][fc][rg] * inv);
    }
}

extern "C" void kernel_launch(void* const* d_in, const int* in_sizes, int n_in,
                              void* d_out, int out_size, void* d_ws, size_t ws_size,
                              hipStream_t stream) {
  const float* x    = (const float*)d_in[0];
  const float* bw   = (const float*)d_in[1];
  const float* sw   = (const float*)d_in[2];
  const float* sc   = (const float*)d_in[3];
  const float* ow   = (const float*)d_in[4];
  const float* ob   = (const float*)d_in[5];
  const float* grid = (const float*)d_in[6];
  const float* rc   = (const float*)d_in[7];
  const float* rs   = (const float*)d_in[8];
  float* out = (float*)d_out;
  char* ws = (char*)d_ws;

  unsigned short* F   = (unsigned short*)(ws);                 // 37,748,736 B
  unsigned short* Wc  = (unsigned short*)(ws + 37748736);      // 56,623,104 B
  unsigned short* Wo  = (unsigned short*)(ws + 94371840);      //  2,097,152 B
  float*          qkv = (float*)(ws + 96468992);               // 25,165,824 B
  unsigned short* Qb  = (unsigned short*)(ws + 121634816);     //  4,194,304 B
  unsigned short* Kb  = (unsigned short*)(ws + 125829120);     //  4,194,304 B
  unsigned short* Vt  = (unsigned short*)(ws + 130023424);     //  4,194,304 B
  unsigned short* ctx = (unsigned short*)(ws + 134217728);     //  4,194,304 B

  kconv_w   <<<dim3(13824), dim3(256), 0, stream>>>(bw, sw, sc, Wc);
  kconv_outw<<<dim3(512),   dim3(256), 0, stream>>>(ow, Wo);
  kfeatures <<<dim3(8192),  dim3(256), 0, stream>>>(x, grid, F);
  kgemm_bt  <<<dim3(16, 24), dim3(256), 0, stream>>>(F, Wc, qkv, (const float*)nullptr, 3072, 9216, 0);
  krope_qk  <<<dim3(4096),  dim3(256), 0, stream>>>(qkv, rc, rs, Qb, Kb);
  kpack_vt  <<<dim3(32, 16), dim3(256), 0, stream>>>(qkv, Vt);
  kattn     <<<dim3(16, 16), dim3(256), 0, stream>>>(Qb, Kb, Vt, ctx);
  kgemm_bt  <<<dim3(16, 8),  dim3(256), 0, stream>>>(ctx, Wo, out, ob, 1024, 1024, 1);
}

// Round 2
// 459.870 us; speedup vs baseline: 1.3869x; 1.3869x over previous
//
#include <hip/hip_runtime.h>

#define DEVI __device__ __forceinline__

typedef float f32x4 __attribute__((ext_vector_type(4)));
typedef __bf16 bf16x8 __attribute__((ext_vector_type(8)));

constexpr int S   = 2048;
constexpr int HID = 1024;
constexpr int HD  = 64;
constexpr int O3  = 3072;
constexpr int KF  = 9216;   // 1024 silu + 1024*8 spline

DEVI unsigned short f2bf(float f) {
  unsigned int u = __float_as_uint(f);
  u = (u + 0x7FFFu + ((u >> 16) & 1u)) >> 16;
  return (unsigned short)u;
}
DEVI float b2f(unsigned int u) { return __uint_as_float(u << 16); }
DEVI float fexp(float x) { return __builtin_amdgcn_exp2f(x * 1.44269504089f); }

DEVI void gload16(const void* g, void* l) {
  __builtin_amdgcn_global_load_lds((const __attribute__((address_space(1))) void*)g,
                                   (__attribute__((address_space(3))) void*)l, 16, 0, 0);
}

// ---- build bf16 combined weight Wc[3072][9216] = [base | spline*scaler] ----
__global__ __launch_bounds__(256) void kconv_w(const float* __restrict__ bw,
    const float* __restrict__ sw, const float* __restrict__ sc,
    unsigned short* __restrict__ Wc) {
  unsigned int t = blockIdx.x * 256 + threadIdx.x;    // < 3072*1152
  unsigned int o = t / 1152, jc = t % 1152;
  unsigned int j = jc * 8;
  float v[8];
  if (j < 1024) {
    const float4* p = (const float4*)(bw + (size_t)o * 1024 + j);
    float4 a = p[0], b = p[1];
    v[0]=a.x; v[1]=a.y; v[2]=a.z; v[3]=a.w; v[4]=b.x; v[5]=b.y; v[6]=b.z; v[7]=b.w;
  } else {
    unsigned int i = (j - 1024) >> 3;
    float s = sc[(size_t)o * 1024 + i];
    const float4* p = (const float4*)(sw + ((size_t)o * 1024 + i) * 8);
    float4 a = p[0], b = p[1];
    v[0]=a.x*s; v[1]=a.y*s; v[2]=a.z*s; v[3]=a.w*s; v[4]=b.x*s; v[5]=b.y*s; v[6]=b.z*s; v[7]=b.w*s;
  }
  union { unsigned short u[8]; uint4 q; } pk;
  #pragma unroll
  for (int c = 0; c < 8; ++c) pk.u[c] = f2bf(v[c]);
  *(uint4*)(Wc + (size_t)o * KF + j) = pk.q;
}

__global__ __launch_bounds__(256) void kconv_outw(const float* __restrict__ ow,
    unsigned short* __restrict__ Wo) {
  unsigned int t = blockIdx.x * 256 + threadIdx.x;    // < 131072
  unsigned int o = t >> 7, j = (t & 127) * 8;
  const float4* p = (const float4*)(ow + (size_t)o * 1024 + j);
  float4 a = p[0], b = p[1];
  float v[8] = {a.x, a.y, a.z, a.w, b.x, b.y, b.z, b.w};
  union { unsigned short u[8]; uint4 q; } pk;
  #pragma unroll
  for (int c = 0; c < 8; ++c) pk.u[c] = f2bf(v[c]);
  *(uint4*)(Wo + (size_t)o * 1024 + j) = pk.q;
}

// ---- features F[2048][9216] bf16 : [silu(x) | b_splines(x)] ----
__global__ __launch_bounds__(256) void kfeatures(const float* __restrict__ x,
    const float* __restrict__ grid, unsigned short* __restrict__ F) {
  unsigned int t = blockIdx.x * 256 + threadIdx.x;    // < 2048*1024
  unsigned int n = t >> 10, i = t & 1023;
  float xv = x[t];
  float sil = xv / (1.f + expf(-xv));
  F[(size_t)n * KF + i] = f2bf(sil);
  float g[12];
  #pragma unroll
  for (int j = 0; j < 12; ++j) g[j] = grid[i * 12 + j];
  float b[11];
  #pragma unroll
  for (int j = 0; j < 11; ++j) b[j] = (xv >= g[j] && xv < g[j + 1]) ? 1.f : 0.f;
  #pragma unroll
  for (int ord = 1; ord <= 3; ++ord)
    #pragma unroll
    for (int j = 0; j + ord < 11; ++j)
      b[j] = (xv - g[j]) / (g[j + ord] - g[j]) * b[j]
           + (g[j + ord + 1] - xv) / (g[j + ord + 1] - g[j + 1]) * b[j + 1];
  union { unsigned short u[8]; uint4 q; } pk;
  #pragma unroll
  for (int c = 0; c < 8; ++c) pk.u[c] = f2bf(b[c]);
  *(uint4*)(F + (size_t)n * KF + 1024 + i * 8) = pk.q;
}

// ---- 128x128 bf16 GEMM: C = A[2048][K] @ W[N][K]^T.
// mode 0: f32 out + bias, single-K.  mode 1: bf16 out, split-K via blockIdx.z
__global__ __launch_bounds__(256) void kgemm_bt(const unsigned short* __restrict__ A,
    const unsigned short* __restrict__ W, void* __restrict__ C,
    const float* __restrict__ bias, int N, int nkPer, int mode) {
  const int bm = blockIdx.x, bn = blockIdx.y;
  const int tid = threadIdx.x;
  const int w = tid >> 6, lane = tid & 63;
  const int l16 = lane & 15, g4 = lane >> 4;
  const int wr = w >> 1, wc = w & 1;
  __shared__ __align__(16) unsigned short As[128 * 32];
  __shared__ __align__(16) unsigned short Bs[128 * 32];
  f32x4 acc[4][4] = {};
  const int K = (mode == 1) ? KF : 1024;
  const int koff = blockIdx.z * nkPer;
  for (int kt = koff; kt < koff + nkPer; ++kt) {
    #pragma unroll
    for (int r = 0; r < 2; ++r) {
      int chunk = r * 256 + w * 64 + lane;
      int row = chunk >> 2, col = (chunk & 3) * 8;
      int ldsoff = (r * 256 + w * 64) * 16;
      gload16(A + (size_t)(bm * 128 + row) * K + kt * 32 + col, (char*)As + ldsoff);
      gload16(W + (size_t)(bn * 128 + row) * K + kt * 32 + col, (char*)Bs + ldsoff);
    }
    asm volatile("s_waitcnt vmcnt(0)" ::: "memory");
    __syncthreads();
    bf16x8 af[4], bf[4];
    #pragma unroll
    for (int f = 0; f < 4; ++f)
      af[f] = *(const bf16x8*)(As + (wr * 64 + f * 16 + l16) * 32 + g4 * 8);
    #pragma unroll
    for (int f = 0; f < 4; ++f)
      bf[f] = *(const bf16x8*)(Bs + (wc * 64 + f * 16 + l16) * 32 + g4 * 8);
    #pragma unroll
    for (int fr = 0; fr < 4; ++fr)
      #pragma unroll
      for (int fc = 0; fc < 4; ++fc)
        acc[fr][fc] = __builtin_amdgcn_mfma_f32_16x16x32_bf16(af[fr], bf[fc], acc[fr][fc], 0, 0, 0);
    __syncthreads();
  }
  if (mode == 0) {
    float* Cf = (float*)C;
    #pragma unroll
    for (int fr = 0; fr < 4; ++fr) {
      int rowb = bm * 128 + wr * 64 + fr * 16 + g4 * 4;
      #pragma unroll
      for (int fc = 0; fc < 4; ++fc) {
        int col = bn * 128 + wc * 64 + fc * 16 + l16;
        float bv = bias[col];
        #pragma unroll
        for (int rg = 0; rg < 4; ++rg)
          Cf[(size_t)(rowb + rg) * N + col] = acc[fr][fc][rg] + bv;
      }
    }
  } else {
    unsigned short* Cb = (unsigned short*)C + (size_t)blockIdx.z * 2048 * N;
    #pragma unroll
    for (int fr = 0; fr < 4; ++fr) {
      int rowb = bm * 128 + wr * 64 + fr * 16 + g4 * 4;
      #pragma unroll
      for (int fc = 0; fc < 4; ++fc) {
        int col = bn * 128 + wc * 64 + fc * 16 + l16;
        #pragma unroll
        for (int rg = 0; rg < 4; ++rg)
          Cb[(size_t)(rowb + rg) * N + col] = f2bf(acc[fr][fc][rg]);
      }
    }
  }
}

// ---- RoPE on q,k (summing split-K partials) -> Qb/Kb [h][n][d]; q scaled 1/8 ----
__global__ __launch_bounds__(256) void krope_qk(const unsigned short* __restrict__ qA,
    const unsigned short* __restrict__ qB, const float* __restrict__ rc,
    const float* __restrict__ rs, unsigned short* __restrict__ Qb,
    unsigned short* __restrict__ Kb) {
  unsigned int t = blockIdx.x * 256 + threadIdx.x;    // < 2048*16*32
  int d = t & 31;
  int h = (t >> 5) & 15;
  int n = t >> 9;
  size_t base = (size_t)n * O3 + h * 192;
  unsigned int a0 = *(const unsigned int*)(qA + base + 2 * d);
  unsigned int a1 = *(const unsigned int*)(qB + base + 2 * d);
  unsigned int e0 = *(const unsigned int*)(qA + base + 64 + 2 * d);
  unsigned int e1 = *(const unsigned int*)(qB + base + 64 + 2 * d);
  float qr = b2f(a0 & 0xffffu) + b2f(a1 & 0xffffu);
  float qi = b2f(a0 >> 16)     + b2f(a1 >> 16);
  float kr = b2f(e0 & 0xffffu) + b2f(e1 & 0xffffu);
  float ki = b2f(e0 >> 16)     + b2f(e1 >> 16);
  float c = rc[n * 32 + d], sn = rs[n * 32 + d];
  unsigned int qp = (unsigned int)f2bf((qr * c - qi * sn) * 0.125f)
                  | ((unsigned int)f2bf((qr * sn + qi * c) * 0.125f) << 16);
  unsigned int kp = (unsigned int)f2bf(kr * c - ki * sn)
                  | ((unsigned int)f2bf(kr * sn + ki * c) << 16);
  *(unsigned int*)(Qb + (size_t)h * S * HD + (size_t)n * HD + 2 * d) = qp;
  *(unsigned int*)(Kb + (size_t)h * S * HD + (size_t)n * HD + 2 * d) = kp;
}

// ---- pack V transposed (summing split-K partials): Vt[h][d][n] bf16 ----
__global__ __launch_bounds__(256) void kpack_vt(const unsigned short* __restrict__ qA,
    const unsigned short* __restrict__ qB, unsigned short* __restrict__ Vt) {
  const int nt = blockIdx.x;   // 0..31
  const int h  = blockIdx.y;   // 0..15
  const int tid = threadIdx.x;
  __shared__ __align__(16) unsigned short T[64][72];
  const int n0 = nt * 64;
  #pragma unroll
  for (int it = 0; it < 2; ++it) {
    int idx = it * 256 + tid;          // 0..511
    int r = idx >> 3;
    int c8 = (idx & 7) * 8;
    size_t base = (size_t)(n0 + r) * O3 + h * 192 + 128 + c8;
    uint4 u0 = *(const uint4*)(qA + base);
    uint4 u1 = *(const uint4*)(qB + base);
    const unsigned short* p0 = (const unsigned short*)&u0;
    const unsigned short* p1 = (const unsigned short*)&u1;
    #pragma unroll
    for (int j = 0; j < 8; ++j)
      T[c8 + j][r] = f2bf(b2f(p0[j]) + b2f(p1[j]));
  }
  __syncthreads();
  #pragma unroll
  for (int it = 0; it < 2; ++it) {
    int idx = it * 256 + tid;          // 0..511
    int dd = idx >> 3;
    int c8 = (idx & 7) * 8;
    *(uint4*)(Vt + (size_t)h * HD * S + (size_t)dd * S + n0 + c8) = *(const uint4*)&T[dd][c8];
  }
}

// ---- flash attention, no-max softmax, swizzled LDS: 4 waves x 16 q-rows ----
__global__ __launch_bounds__(256) void kattn(const unsigned short* __restrict__ Qb,
    const unsigned short* __restrict__ Kb, const unsigned short* __restrict__ Vt,
    unsigned short* __restrict__ ctx) {
  const int qb = blockIdx.x, h = blockIdx.y;
  const int tid = threadIdx.x, w = tid >> 6, lane = tid & 63;
  const int l16 = lane & 15, g4 = lane >> 4;
  __shared__ __align__(16) unsigned short Ks[64 * 64];
  __shared__ __align__(16) unsigned short Vs[64 * 64];
  __shared__ __align__(16) unsigned short Ps[4][16 * 64];
  const unsigned short* Qh = Qb + (size_t)h * S * HD;
  const unsigned short* Kh = Kb + (size_t)h * S * HD;
  const unsigned short* Vh = Vt + (size_t)h * HD * S;
  bf16x8 qf[2];
  #pragma unroll
  for (int ks = 0; ks < 2; ++ks)
    qf[ks] = *(const bf16x8*)(Qh + (size_t)(qb * 64 + w * 16 + l16) * HD + ks * 32 + g4 * 8);
  f32x4 o[4] = {};
  float lp[4] = {0.f, 0.f, 0.f, 0.f};

  for (int t = 0; t < S / 64; ++t) {
    int kv0 = t * 64;
    #pragma unroll
    for (int r = 0; r < 2; ++r) {
      int chunk = r * 256 + w * 64 + lane;
      int row = chunk >> 3;
      int c8 = ((chunk ^ row) & 7) * 8;            // pre-swizzled global source
      int ldsoff = (r * 256 + w * 64) * 16;        // wave-uniform; HW adds lane*16
      gload16(Kh + (size_t)(kv0 + row) * HD + c8, (char*)Ks + ldsoff);
      gload16(Vh + (size_t)row * S + kv0 + c8, (char*)Vs + ldsoff);
    }
    asm volatile("s_waitcnt vmcnt(0)" ::: "memory");
    __syncthreads();
    f32x4 s[4] = {};
    #pragma unroll
    for (int fc = 0; fc < 4; ++fc) {
      int rw = fc * 16 + l16;
      #pragma unroll
      for (int ks = 0; ks < 2; ++ks) {
        bf16x8 bk = *(const bf16x8*)(Ks + rw * 64 + (((ks * 4 + g4) ^ (l16 & 7)) * 8));
        s[fc] = __builtin_amdgcn_mfma_f32_16x16x32_bf16(qf[ks], bk, s[fc], 0, 0, 0);
      }
    }
    #pragma unroll
    for (int fc = 0; fc < 4; ++fc)
      #pragma unroll
      for (int rg = 0; rg < 4; ++rg) {
        float p = fexp(s[fc][rg]);
        lp[rg] += p;
        int row = g4 * 4 + rg;
        Ps[w][row * 64 + ((fc * 2 + (l16 >> 3)) ^ (row & 7)) * 8 + (l16 & 7)] = f2bf(p);
      }
    #pragma unroll
    for (int ks = 0; ks < 2; ++ks) {
      bf16x8 ap = *(const bf16x8*)(Ps[w] + l16 * 64 + (((ks * 4 + g4) ^ (l16 & 7)) * 8));
      #pragma unroll
      for (int fc = 0; fc < 4; ++fc) {
        int rw = fc * 16 + l16;
        bf16x8 bv = *(const bf16x8*)(Vs + rw * 64 + (((ks * 4 + g4) ^ (l16 & 7)) * 8));
        o[fc] = __builtin_amdgcn_mfma_f32_16x16x32_bf16(ap, bv, o[fc], 0, 0, 0);
      }
    }
    __syncthreads();
  }
  #pragma unroll
  for (int rg = 0; rg < 4; ++rg) {
    float l = lp[rg];
    l += __shfl_xor(l, 1, 64);
    l += __shfl_xor(l, 2, 64);
    l += __shfl_xor(l, 4, 64);
    l += __shfl_xor(l, 8, 64);
    float inv = 1.f / l;
    int row = qb * 64 + w * 16 + g4 * 4 + rg;
    #pragma unroll
    for (int fc = 0; fc < 4; ++fc)
      ctx[(size_t)row * HID + h * HD + fc * 16 + l16] = f2bf(o[fc][rg] * inv);
  }
}

extern "C" void kernel_launch(void* const* d_in, const int* in_sizes, int n_in,
                              void* d_out, int out_size, void* d_ws, size_t ws_size,
                              hipStream_t stream) {
  const float* x    = (const float*)d_in[0];
  const float* bw   = (const float*)d_in[1];
  const float* sw   = (const float*)d_in[2];
  const float* sc   = (const float*)d_in[3];
  const float* ow   = (const float*)d_in[4];
  const float* ob   = (const float*)d_in[5];
  const float* grid = (const float*)d_in[6];
  const float* rc   = (const float*)d_in[7];
  const float* rs   = (const float*)d_in[8];
  float* out = (float*)d_out;
  char* ws = (char*)d_ws;

  unsigned short* F    = (unsigned short*)(ws);                 // 37,748,736 B
  unsigned short* Wc   = (unsigned short*)(ws + 37748736);      // 56,623,104 B
  unsigned short* Wo   = (unsigned short*)(ws + 94371840);      //  2,097,152 B
  unsigned short* qkv0 = (unsigned short*)(ws + 96468992);      // 12,582,912 B (split 0)
  unsigned short* qkv1 = qkv0 + (size_t)2048 * O3;              // 12,582,912 B (split 1)
  unsigned short* Qb   = (unsigned short*)(ws + 121634816);     //  4,194,304 B
  unsigned short* Kb   = (unsigned short*)(ws + 125829120);     //  4,194,304 B
  unsigned short* Vt   = (unsigned short*)(ws + 130023424);     //  4,194,304 B
  unsigned short* ctx  = (unsigned short*)(ws + 134217728);     //  4,194,304 B

  kconv_w   <<<dim3(13824), dim3(256), 0, stream>>>(bw, sw, sc, Wc);
  kconv_outw<<<dim3(512),   dim3(256), 0, stream>>>(ow, Wo);
  kfeatures <<<dim3(8192),  dim3(256), 0, stream>>>(x, grid, F);
  kgemm_bt  <<<dim3(16, 24, 2), dim3(256), 0, stream>>>(F, Wc, qkv0, (const float*)nullptr, 3072, 144, 1);
  krope_qk  <<<dim3(4096),  dim3(256), 0, stream>>>(qkv0, qkv1, rc, rs, Qb, Kb);
  kpack_vt  <<<dim3(32, 16), dim3(256), 0, stream>>>(qkv0, qkv1, Vt);
  kattn     <<<dim3(32, 16), dim3(256), 0, stream>>>(Qb, Kb, Vt, ctx);
  kgemm_bt  <<<dim3(16, 8, 1),  dim3(256), 0, stream>>>(ctx, Wo, out, ob, 1024, 32, 0);
}